// Round 9
// baseline (308.328 us; speedup 1.0000x reference)
//
#include <hip/hip_runtime.h>
#include <stdint.h>

#define NB 4
#define NC 256
#define NCI 128
#define NN 4096

typedef __attribute__((ext_vector_type(8))) short short8;
typedef __attribute__((ext_vector_type(4))) float f32x4;

__device__ __forceinline__ float bf2f(unsigned short u) {
    union { unsigned int i; float f; } v; v.i = ((unsigned int)u) << 16; return v.f;
}
__device__ __forceinline__ unsigned short f2bf(float f) {
    union { unsigned int i; float f; } v; v.f = f;
    unsigned int b = v.i;
    b += 0x7FFFu + ((b >> 16) & 1u);   // RNE
    return (unsigned short)(b >> 16);
}

// ---------------------------------------------------------------- sentinel fill
__global__ void k_fill(float* __restrict__ p, float v, int n) {
    int i = blockIdx.x * blockDim.x + threadIdx.x;
    if (i < n) p[i] = v;
}

// ---------------------------------------------------------------- K0: weight split/convert
// WtH/WtL pre-scaled by log2(e) so attention logits live in the exp2 domain.
// m: 0=Wt(H+L,scaled) 1=Wp(H+L) 2=Wg(H) 3=Wo(H). 32768 elems each.
__global__ __launch_bounds__(256) void k_split(
    const float* __restrict__ Wt, const float* __restrict__ Wp,
    const float* __restrict__ Wg, const float* __restrict__ Wo,
    unsigned short* __restrict__ wbuf) {
    const float LOG2E = 1.4426950408889634f;
    int m = blockIdx.y;
    int i = blockIdx.x * 256 + threadIdx.x;
    if (m == 0) {
        float v = Wt[i] * LOG2E;
        unsigned short h = f2bf(v);
        wbuf[i] = h;                       // WtH
        wbuf[32768 + i] = f2bf(v - bf2f(h));   // WtL
    } else if (m == 1) {
        float v = Wp[i];
        unsigned short h = f2bf(v);
        wbuf[65536 + i] = h;               // WpH
        wbuf[98304 + i] = f2bf(v - bf2f(h));   // WpL
    } else if (m == 2) {
        wbuf[131072 + i] = f2bf(Wg[i]);    // WgH
    } else {
        wbuf[163840 + i] = f2bf(Wo[i]);    // WoH
    }
}

// ---------------------------------------------------------------- K1: phi (hi/lo) + g projections
// Grid (64 n-tiles of 64, B). A-frags (weights, k-contig) straight from global
// bf16; x transpose-split staged in LDS with paired-row b32 writes.
__global__ __launch_bounds__(256, 1) void k_qkv2(
    const float* __restrict__ x,
    const unsigned short* __restrict__ WpH, const unsigned short* __restrict__ WpL,
    const unsigned short* __restrict__ WgH,
    const float* __restrict__ bp, const float* __restrict__ bg,
    unsigned short* __restrict__ phiH, unsigned short* __restrict__ phiL,
    unsigned short* __restrict__ gout) {
    __shared__ __align__(16) unsigned short sXh[64 * 72];
    __shared__ __align__(16) unsigned short sXl[64 * 72];
    const int b = blockIdx.y, n0 = blockIdx.x * 64;
    const int tid = threadIdx.x, lane = tid & 63, wave = tid >> 6;
    const int col = lane & 15, quad = lane >> 4;
    const int wm = wave * 32;

    f32x4 accP[2][4], accG[2][4];
#pragma unroll
    for (int i = 0; i < 2; i++)
#pragma unroll
        for (int j = 0; j < 4; j++)
#pragma unroll
            for (int e = 0; e < 4; e++) { accP[i][j][e] = 0.f; accG[i][j][e] = 0.f; }

    for (int c0 = 0; c0 < NC; c0 += 64) {
        __syncthreads();   // prev iter's ds_reads done before restage
        // A-frags: issue global loads early (consumed after barrier)
        short8 ah[2][2], al[2][2], ag[2][2];
#pragma unroll
        for (int ks = 0; ks < 2; ks++)
#pragma unroll
            for (int i = 0; i < 2; i++) {
                size_t w = (size_t)(wm + i * 16 + col) * NC + c0 + ks * 32 + quad * 8;
                ah[ks][i] = *(const short8*)&WpH[w];
                al[ks][i] = *(const short8*)&WpL[w];
                ag[ks][i] = *(const short8*)&WgH[w];
            }
        // x transpose-split: rows 2cp,2cp+1 -> paired b32 writes
#pragma unroll
        for (int rr = 0; rr < 2; rr++) {
            int q = tid + rr * 256;
            int cp = q >> 4, n4 = (q & 15) * 4;
            const float* xp = x + ((size_t)(b * NC + c0 + 2 * cp)) * NN + n0 + n4;
            float4 a = *(const float4*)xp;
            float4 c = *(const float4*)(xp + NN);
            float av[4] = { a.x, a.y, a.z, a.w };
            float cv[4] = { c.x, c.y, c.z, c.w };
#pragma unroll
            for (int j = 0; j < 4; j++) {
                unsigned short ha = f2bf(av[j]), hc = f2bf(cv[j]);
                unsigned short la = f2bf(av[j] - bf2f(ha)), lc = f2bf(cv[j] - bf2f(hc));
                *(unsigned int*)&sXh[(n4 + j) * 72 + 2 * cp] =
                    (unsigned int)ha | ((unsigned int)hc << 16);
                *(unsigned int*)&sXl[(n4 + j) * 72 + 2 * cp] =
                    (unsigned int)la | ((unsigned int)lc << 16);
            }
        }
        __syncthreads();
#pragma unroll
        for (int ks = 0; ks < 2; ks++)
#pragma unroll
            for (int j = 0; j < 4; j++) {
                short8 bh = *(const short8*)&sXh[(j * 16 + col) * 72 + ks * 32 + quad * 8];
                short8 bl = *(const short8*)&sXl[(j * 16 + col) * 72 + ks * 32 + quad * 8];
#pragma unroll
                for (int i = 0; i < 2; i++) {
                    accP[i][j] = __builtin_amdgcn_mfma_f32_16x16x32_bf16(ah[ks][i], bh, accP[i][j], 0, 0, 0);
                    accP[i][j] = __builtin_amdgcn_mfma_f32_16x16x32_bf16(ah[ks][i], bl, accP[i][j], 0, 0, 0);
                    accP[i][j] = __builtin_amdgcn_mfma_f32_16x16x32_bf16(al[ks][i], bh, accP[i][j], 0, 0, 0);
                    accG[i][j] = __builtin_amdgcn_mfma_f32_16x16x32_bf16(ag[ks][i], bh, accG[i][j], 0, 0, 0);
                }
            }
    }
#pragma unroll
    for (int i = 0; i < 2; i++) {
        int mrow = wm + i * 16 + quad * 4;
#pragma unroll
        for (int j = 0; j < 4; j++) {
            int n = n0 + j * 16 + col;
            unsigned short h[4], l[4];
#pragma unroll
            for (int e = 0; e < 4; e++) {
                float v = accP[i][j][e] + bp[mrow + e];
                h[e] = f2bf(v);
                l[e] = f2bf(v - bf2f(h[e]));
            }
            uint2 hv, lv;
            hv.x = (unsigned int)h[0] | ((unsigned int)h[1] << 16);
            hv.y = (unsigned int)h[2] | ((unsigned int)h[3] << 16);
            lv.x = (unsigned int)l[0] | ((unsigned int)l[1] << 16);
            lv.y = (unsigned int)l[2] | ((unsigned int)l[3] << 16);
            *(uint2*)&phiH[((size_t)(b * NN + n)) * NCI + mrow] = hv;
            *(uint2*)&phiL[((size_t)(b * NN + n)) * NCI + mrow] = lv;
#pragma unroll
            for (int r = 0; r < 4; r++)
                gout[((size_t)(b * NCI + mrow + r)) * NN + n] = f2bf(accG[i][j][r] + bg[mrow + r]);
        }
    }
}

// ---------------------------------------------------------------- K2: fused attention
// Per block: batch b, 64 queries (XCD-swizzled). Prologue computes log2e-scaled
// theta (split conv, bf16 weight copies); main K-loop register-prefetches the
// next phi/g tile during compute; epilogue fuses out-proj + bias + residual.
__global__ __launch_bounds__(256, 1) void k_attn(
    const float* __restrict__ x,
    const unsigned short* __restrict__ WtH, const unsigned short* __restrict__ WtL,
    const float* __restrict__ bt,
    const unsigned short* __restrict__ phiH, const unsigned short* __restrict__ phiL,
    const unsigned short* __restrict__ gmat,
    const unsigned short* __restrict__ WoH, const float* __restrict__ bo,
    float* __restrict__ y) {
    const float LOG2E = 1.4426950408889634f;
    __shared__ __align__(16) char smem[97280];
    unsigned short* sThH = (unsigned short*)(smem);            // [64 q][136]
    unsigned short* sThL = (unsigned short*)(smem + 17408);
    unsigned short* sWth = (unsigned short*)(smem + 34816);    // prologue [128 ci][72]
    unsigned short* sWtl = (unsigned short*)(smem + 53248);
    unsigned short* sXh  = (unsigned short*)(smem + 71680);    // prologue [64 n][72]
    unsigned short* sXl  = (unsigned short*)(smem + 80896);
    unsigned short* sPhiH = (unsigned short*)(smem + 34816);   // main [64 m][136]
    unsigned short* sPhiL = (unsigned short*)(smem + 52224);
    unsigned short* sG    = (unsigned short*)(smem + 69632);   // main [128 c][72]
    unsigned short* sPall = (unsigned short*)(smem + 88064);   // [4 waves][16 q][72]
    unsigned short* sO    = (unsigned short*)(smem);           // epilogue [64 q][136]
    unsigned short* sWo   = (unsigned short*)(smem + 17408);   // epilogue [64 o][136]

    const int id = blockIdx.x;
    const int xcd = id & 7, slot = id >> 3;
    const int b = xcd >> 1;
    const int n0 = (slot * 2 + (xcd & 1)) * 64;

    const int tid = threadIdx.x, lane = tid & 63, wave = tid >> 6;
    const int col = lane & 15, quad = lane >> 4;
    unsigned short* sP = sPall + wave * 16 * 72;
    const int bsrc = (col >> 2) << 4, rsel = col & 3;

    // ---------------- prologue: theta (log2e-scaled), f32-grade split
    f32x4 th[2][4];
#pragma unroll
    for (int i = 0; i < 2; i++)
#pragma unroll
        for (int j = 0; j < 4; j++)
#pragma unroll
            for (int e = 0; e < 4; e++) th[i][j][e] = 0.f;
    const int wci = wave * 32;

    for (int c0 = 0; c0 < NC; c0 += 64) {
        // Wt tiles: pure bf16 copies
#pragma unroll
        for (int i = 0; i < 4; i++) {
            int q = tid + i * 256;
            int row = q >> 3, seg = q & 7;
            *(uint4*)&sWth[row * 72 + seg * 8] = *(const uint4*)&WtH[(size_t)row * NC + c0 + seg * 8];
            *(uint4*)&sWtl[row * 72 + seg * 8] = *(const uint4*)&WtL[(size_t)row * NC + c0 + seg * 8];
        }
        // x transpose-split, paired rows
#pragma unroll
        for (int rr = 0; rr < 2; rr++) {
            int q = tid + rr * 256;
            int cp = q >> 4, n4 = (q & 15) * 4;
            const float* xp = x + ((size_t)(b * NC + c0 + 2 * cp)) * NN + n0 + n4;
            float4 a = *(const float4*)xp;
            float4 c = *(const float4*)(xp + NN);
            float av[4] = { a.x, a.y, a.z, a.w };
            float cv[4] = { c.x, c.y, c.z, c.w };
#pragma unroll
            for (int j = 0; j < 4; j++) {
                unsigned short ha = f2bf(av[j]), hc = f2bf(cv[j]);
                unsigned short la = f2bf(av[j] - bf2f(ha)), lc = f2bf(cv[j] - bf2f(hc));
                *(unsigned int*)&sXh[(n4 + j) * 72 + 2 * cp] =
                    (unsigned int)ha | ((unsigned int)hc << 16);
                *(unsigned int*)&sXl[(n4 + j) * 72 + 2 * cp] =
                    (unsigned int)la | ((unsigned int)lc << 16);
            }
        }
        __syncthreads();
#pragma unroll
        for (int ks = 0; ks < 2; ks++) {
            short8 ah[2], al[2], bh[4], bl[4];
#pragma unroll
            for (int i = 0; i < 2; i++) {
                ah[i] = *(const short8*)&sWth[(wci + i * 16 + col) * 72 + ks * 32 + quad * 8];
                al[i] = *(const short8*)&sWtl[(wci + i * 16 + col) * 72 + ks * 32 + quad * 8];
            }
#pragma unroll
            for (int j = 0; j < 4; j++) {
                bh[j] = *(const short8*)&sXh[(j * 16 + col) * 72 + ks * 32 + quad * 8];
                bl[j] = *(const short8*)&sXl[(j * 16 + col) * 72 + ks * 32 + quad * 8];
            }
#pragma unroll
            for (int i = 0; i < 2; i++)
#pragma unroll
                for (int j = 0; j < 4; j++) {
                    th[i][j] = __builtin_amdgcn_mfma_f32_16x16x32_bf16(ah[i], bh[j], th[i][j], 0, 0, 0);
                    th[i][j] = __builtin_amdgcn_mfma_f32_16x16x32_bf16(ah[i], bl[j], th[i][j], 0, 0, 0);
                    th[i][j] = __builtin_amdgcn_mfma_f32_16x16x32_bf16(al[i], bh[j], th[i][j], 0, 0, 0);
                }
        }
        __syncthreads();
    }
    // bias (scaled) + split -> sTh
#pragma unroll
    for (int i = 0; i < 2; i++) {
        int ci = wci + i * 16 + quad * 4;
#pragma unroll
        for (int j = 0; j < 4; j++) {
            int q = j * 16 + col;
            unsigned short h[4], l[4];
#pragma unroll
            for (int e = 0; e < 4; e++) {
                float v = th[i][j][e] + bt[ci + e] * LOG2E;
                h[e] = f2bf(v);
                l[e] = f2bf(v - bf2f(h[e]));
            }
            uint2 hv, lv;
            hv.x = (unsigned int)h[0] | ((unsigned int)h[1] << 16);
            hv.y = (unsigned int)h[2] | ((unsigned int)h[3] << 16);
            lv.x = (unsigned int)l[0] | ((unsigned int)l[1] << 16);
            lv.y = (unsigned int)l[2] | ((unsigned int)l[3] << 16);
            *(uint2*)&sThH[q * 136 + ci] = hv;
            *(uint2*)&sThL[q * 136 + ci] = lv;
        }
    }
    __syncthreads();
    short8 qh[4], ql[4];
#pragma unroll
    for (int ks = 0; ks < 4; ks++) {
        qh[ks] = *(const short8*)&sThH[(wave * 16 + col) * 136 + ks * 32 + quad * 8];
        ql[ks] = *(const short8*)&sThL[(wave * 16 + col) * 136 + ks * 32 + quad * 8];
    }

    // ---------------- main K-loop with register prefetch
    f32x4 oacc[8];
#pragma unroll
    for (int i = 0; i < 8; i++)
#pragma unroll
        for (int e = 0; e < 4; e++) oacc[i][e] = 0.f;
    float li[4] = { 0.f, 0.f, 0.f, 0.f };

    uint4 rPH[4], rPL[4], rG[4];
    auto load_tile = [&](int m0) {
#pragma unroll
        for (int i = 0; i < 4; i++) {
            int q = tid + i * 256;
            int row = q >> 4, seg = q & 15;
            size_t src = ((size_t)(b * NN + m0 + row)) * NCI + seg * 8;
            rPH[i] = *(const uint4*)&phiH[src];
            rPL[i] = *(const uint4*)&phiL[src];
        }
#pragma unroll
        for (int i = 0; i < 4; i++) {
            int q = tid + i * 256;
            int row = q >> 3, seg = q & 7;
            rG[i] = *(const uint4*)&gmat[((size_t)(b * NCI + row)) * NN + m0 + seg * 8];
        }
    };
    load_tile(0);

    for (int m0 = 0; m0 < NN; m0 += 64) {
        __syncthreads();   // all waves done reading prev tile's LDS
#pragma unroll
        for (int i = 0; i < 4; i++) {
            int q = tid + i * 256;
            int row = q >> 4, seg = q & 15;
            *(uint4*)&sPhiH[row * 136 + seg * 8] = rPH[i];
            *(uint4*)&sPhiL[row * 136 + seg * 8] = rPL[i];
        }
#pragma unroll
        for (int i = 0; i < 4; i++) {
            int q = tid + i * 256;
            int row = q >> 3, seg = q & 7;
            *(uint4*)&sG[row * 72 + seg * 8] = rG[i];
        }
        if (m0 + 64 < NN) load_tile(m0 + 64);   // prefetch next tile during compute
        __syncthreads();

        f32x4 S[4];
#pragma unroll
        for (int mtl = 0; mtl < 4; mtl++) {
            f32x4 a;
#pragma unroll
            for (int e = 0; e < 4; e++) a[e] = 0.f;
#pragma unroll
            for (int ks = 0; ks < 4; ks++) {
                short8 ph = *(const short8*)&sPhiH[(mtl * 16 + col) * 136 + ks * 32 + quad * 8];
                short8 pl = *(const short8*)&sPhiL[(mtl * 16 + col) * 136 + ks * 32 + quad * 8];
                a = __builtin_amdgcn_mfma_f32_16x16x32_bf16(qh[ks], ph, a, 0, 0, 0);
                a = __builtin_amdgcn_mfma_f32_16x16x32_bf16(qh[ks], pl, a, 0, 0, 0);
                a = __builtin_amdgcn_mfma_f32_16x16x32_bf16(ql[ks], ph, a, 0, 0, 0);
            }
            S[mtl] = a;
        }
        // exp2 (logits pre-scaled by log2e; bounded ~100 < 128), row-sum, P->LDS
        float pv[4][4];
#pragma unroll
        for (int r = 0; r < 4; r++) {
            float rs = 0.f;
#pragma unroll
            for (int mtl = 0; mtl < 4; mtl++) {
                float p = exp2f(S[mtl][r]);
                pv[mtl][r] = p;
                rs += p;
            }
#pragma unroll
            for (int off = 1; off < 16; off <<= 1) rs += __shfl_xor(rs, off);
            li[r] += rs;
        }
#pragma unroll
        for (int mtl = 0; mtl < 4; mtl++)
#pragma unroll
            for (int r = 0; r < 4; r++)
                sP[(quad * 4 + r) * 72 + mtl * 16 + col] = f2bf(pv[mtl][r]);
        // sP produced and consumed by the SAME wave: DS-pipe order suffices, no barrier
        short8 pf[2];
#pragma unroll
        for (int ks = 0; ks < 2; ks++)
            pf[ks] = *(const short8*)&sP[col * 72 + ks * 32 + quad * 8];
#pragma unroll
        for (int ct = 0; ct < 8; ct++)
#pragma unroll
            for (int ks = 0; ks < 2; ks++) {
                short8 af = *(const short8*)&sG[(ct * 16 + col) * 72 + ks * 32 + quad * 8];
                oacc[ct] = __builtin_amdgcn_mfma_f32_16x16x32_bf16(af, pf[ks], oacc[ct], 0, 0, 0);
            }
    }
    __syncthreads();

    // ---------------- epilogue: normalize, O -> LDS, out-proj + bias + residual
    float inv;
    {
        float i0 = 1.0f / li[0], i1 = 1.0f / li[1], i2 = 1.0f / li[2], i3 = 1.0f / li[3];
        float b0 = __shfl(i0, bsrc), b1 = __shfl(i1, bsrc);
        float b2 = __shfl(i2, bsrc), b3 = __shfl(i3, bsrc);
        inv = (rsel == 0) ? b0 : (rsel == 1) ? b1 : (rsel == 2) ? b2 : b3;
    }
    {
        int q = wave * 16 + col;
#pragma unroll
        for (int ct = 0; ct < 8; ct++) {
            int ci = ct * 16 + quad * 4;
            uint2 v;
            unsigned short p0 = f2bf(oacc[ct][0] * inv);
            unsigned short p1 = f2bf(oacc[ct][1] * inv);
            unsigned short p2 = f2bf(oacc[ct][2] * inv);
            unsigned short p3 = f2bf(oacc[ct][3] * inv);
            v.x = (unsigned int)p0 | ((unsigned int)p1 << 16);
            v.y = (unsigned int)p2 | ((unsigned int)p3 << 16);
            *(uint2*)&sO[q * 136 + ci] = v;
        }
    }
    __syncthreads();

    for (int ot = 0; ot < 4; ot++) {
        // Wo tile: pure bf16 copy
#pragma unroll
        for (int i = 0; i < 4; i++) {
            int q = tid + i * 256;
            int row = q >> 4, seg = q & 15;
            *(uint4*)&sWo[row * 136 + seg * 8] =
                *(const uint4*)&WoH[(size_t)(ot * 64 + row) * NCI + seg * 8];
        }
        __syncthreads();
        f32x4 acc[4];
#pragma unroll
        for (int j = 0; j < 4; j++)
#pragma unroll
            for (int e = 0; e < 4; e++) acc[j][e] = 0.f;
#pragma unroll
        for (int ks = 0; ks < 4; ks++) {
            short8 af = *(const short8*)&sWo[(wave * 16 + col) * 136 + ks * 32 + quad * 8];
#pragma unroll
            for (int j = 0; j < 4; j++) {
                short8 bf = *(const short8*)&sO[(j * 16 + col) * 136 + ks * 32 + quad * 8];
                acc[j] = __builtin_amdgcn_mfma_f32_16x16x32_bf16(af, bf, acc[j], 0, 0, 0);
            }
        }
#pragma unroll
        for (int j = 0; j < 4; j++) {
#pragma unroll
            for (int e = 0; e < 4; e++) {
                int o = ot * 64 + wave * 16 + quad * 4 + e;
                size_t idx = ((size_t)(b * NC + o)) * NN + n0 + j * 16 + col;
                y[idx] = acc[j][e] + bo[o] + x[idx];
            }
        }
        __syncthreads();
    }
}

// ---------------------------------------------------------------- launch
// ws: phiH(4M) + phiL(4M) + g(4M) + split weights(384K) ~ 12.4 MB of >=16 MB.
extern "C" void kernel_launch(void* const* d_in, const int* in_sizes, int n_in,
                              void* d_out, int out_size, void* d_ws, size_t ws_size,
                              hipStream_t stream) {
    float* y = (float*)d_out;

    bool sizes_ok = (n_in == 9) &&
        in_sizes[0] == NB * NC * NN && in_sizes[1] == NCI * NC && in_sizes[2] == NCI &&
        in_sizes[3] == NCI * NC && in_sizes[4] == NCI && in_sizes[5] == NCI * NC &&
        in_sizes[6] == NCI && in_sizes[7] == NC * NCI && in_sizes[8] == NC &&
        out_size == NB * NC * NN;
    if (!sizes_ok) {
        k_fill<<<(out_size + 255) / 256, 256, 0, stream>>>(y, 777.0f, out_size);
        return;
    }
    if (ws_size < (size_t)16 * 1024 * 1024) {
        k_fill<<<(out_size + 255) / 256, 256, 0, stream>>>(y, 555.0f, out_size);
        return;
    }

    const float* x  = (const float*)d_in[0];
    const float* tw = (const float*)d_in[1];
    const float* tb = (const float*)d_in[2];
    const float* pw = (const float*)d_in[3];
    const float* pb = (const float*)d_in[4];
    const float* gw = (const float*)d_in[5];
    const float* gb = (const float*)d_in[6];
    const float* ow = (const float*)d_in[7];
    const float* obias = (const float*)d_in[8];

    unsigned short* ws16 = (unsigned short*)d_ws;
    unsigned short* phiH = ws16;                 // [B][N][Ci] bf16 hi
    unsigned short* phiL = ws16 + 2097152;       // [B][N][Ci] bf16 lo
    unsigned short* g    = ws16 + 4194304;       // [B][Ci][N] bf16
    unsigned short* wbuf = ws16 + 6291456;       // WtH,WtL,WpH,WpL,WgH,WoH (32768 each)
    unsigned short* WtH = wbuf,           *WtL = wbuf + 32768;
    unsigned short* WpH = wbuf + 65536,   *WpL = wbuf + 98304;
    unsigned short* WgH = wbuf + 131072,  *WoH = wbuf + 163840;

    k_split<<<dim3(128, 4), 256, 0, stream>>>(tw, pw, gw, ow, wbuf);
    k_qkv2<<<dim3(64, NB), 256, 0, stream>>>(x, WpH, WpL, WgH, pb, gb, phiH, phiL, g);
    k_attn<<<dim3(256), 256, 0, stream>>>(x, WtH, WtL, tb, phiH, phiL, g, WoH, obias, y);
}

// Round 10
// 251.870 us; speedup vs baseline: 1.2242x; 1.2242x over previous
//
#include <hip/hip_runtime.h>
#include <stdint.h>

#define NB 4
#define NC 256
#define NCI 128
#define NN 4096

typedef __attribute__((ext_vector_type(8))) short short8;
typedef __attribute__((ext_vector_type(4))) float f32x4;

__device__ __forceinline__ float bf2f(unsigned short u) {
    union { unsigned int i; float f; } v; v.i = ((unsigned int)u) << 16; return v.f;
}
__device__ __forceinline__ unsigned short f2bf(float f) {
    union { unsigned int i; float f; } v; v.f = f;
    unsigned int b = v.i;
    b += 0x7FFFu + ((b >> 16) & 1u);   // RNE
    return (unsigned short)(b >> 16);
}

// ---------------------------------------------------------------- sentinel fill
__global__ void k_fill(float* __restrict__ p, float v, int n) {
    int i = blockIdx.x * blockDim.x + threadIdx.x;
    if (i < n) p[i] = v;
}

// ---------------------------------------------------------------- K0: weight split/convert
__global__ __launch_bounds__(256) void k_split(
    const float* __restrict__ Wt, const float* __restrict__ Wp,
    const float* __restrict__ Wg, const float* __restrict__ Wo,
    unsigned short* __restrict__ wbuf) {
    const float LOG2E = 1.4426950408889634f;
    int m = blockIdx.y;
    int i = blockIdx.x * 256 + threadIdx.x;
    if (m == 0) {
        float v = Wt[i] * LOG2E;
        unsigned short h = f2bf(v);
        wbuf[i] = h;
        wbuf[32768 + i] = f2bf(v - bf2f(h));
    } else if (m == 1) {
        float v = Wp[i];
        unsigned short h = f2bf(v);
        wbuf[65536 + i] = h;
        wbuf[98304 + i] = f2bf(v - bf2f(h));
    } else if (m == 2) {
        wbuf[131072 + i] = f2bf(Wg[i]);
    } else {
        wbuf[163840 + i] = f2bf(Wo[i]);
    }
}

// ---------------------------------------------------------------- K1: phi (hi/lo) + g projections
// 32-wide n-tiles, grid 512 -> 2 blocks/CU for latency hiding.
__global__ __launch_bounds__(256, 2) void k_qkv2(
    const float* __restrict__ x,
    const unsigned short* __restrict__ WpH, const unsigned short* __restrict__ WpL,
    const unsigned short* __restrict__ WgH,
    const float* __restrict__ bp, const float* __restrict__ bg,
    unsigned short* __restrict__ phiH, unsigned short* __restrict__ phiL,
    unsigned short* __restrict__ gout) {
    __shared__ __align__(16) unsigned short sXh[32 * 72];
    __shared__ __align__(16) unsigned short sXl[32 * 72];
    const int b = blockIdx.y, n0 = blockIdx.x * 32;
    const int tid = threadIdx.x, lane = tid & 63, wave = tid >> 6;
    const int col = lane & 15, quad = lane >> 4;
    const int wm = wave * 32;

    f32x4 accP[2][2], accG[2][2];
#pragma unroll
    for (int i = 0; i < 2; i++)
#pragma unroll
        for (int j = 0; j < 2; j++)
#pragma unroll
            for (int e = 0; e < 4; e++) { accP[i][j][e] = 0.f; accG[i][j][e] = 0.f; }

    for (int c0 = 0; c0 < NC; c0 += 64) {
        __syncthreads();
        // A-frags straight from global bf16 (k-contig)
        short8 ah[2][2], al[2][2], ag[2][2];
#pragma unroll
        for (int ks = 0; ks < 2; ks++)
#pragma unroll
            for (int i = 0; i < 2; i++) {
                size_t w = (size_t)(wm + i * 16 + col) * NC + c0 + ks * 32 + quad * 8;
                ah[ks][i] = *(const short8*)&WpH[w];
                al[ks][i] = *(const short8*)&WpL[w];
                ag[ks][i] = *(const short8*)&WgH[w];
            }
        // x transpose-split: 32 n x 64 c, paired rows
        {
            int cp = tid >> 3, n4 = (tid & 7) * 4;
            const float* xp = x + ((size_t)(b * NC + c0 + 2 * cp)) * NN + n0 + n4;
            float4 a = *(const float4*)xp;
            float4 c = *(const float4*)(xp + NN);
            float av[4] = { a.x, a.y, a.z, a.w };
            float cv[4] = { c.x, c.y, c.z, c.w };
#pragma unroll
            for (int j = 0; j < 4; j++) {
                unsigned short ha = f2bf(av[j]), hc = f2bf(cv[j]);
                unsigned short la = f2bf(av[j] - bf2f(ha)), lc = f2bf(cv[j] - bf2f(hc));
                *(unsigned int*)&sXh[(n4 + j) * 72 + 2 * cp] =
                    (unsigned int)ha | ((unsigned int)hc << 16);
                *(unsigned int*)&sXl[(n4 + j) * 72 + 2 * cp] =
                    (unsigned int)la | ((unsigned int)lc << 16);
            }
        }
        __syncthreads();
#pragma unroll
        for (int ks = 0; ks < 2; ks++)
#pragma unroll
            for (int j = 0; j < 2; j++) {
                short8 bh = *(const short8*)&sXh[(j * 16 + col) * 72 + ks * 32 + quad * 8];
                short8 bl = *(const short8*)&sXl[(j * 16 + col) * 72 + ks * 32 + quad * 8];
#pragma unroll
                for (int i = 0; i < 2; i++) {
                    accP[i][j] = __builtin_amdgcn_mfma_f32_16x16x32_bf16(ah[ks][i], bh, accP[i][j], 0, 0, 0);
                    accP[i][j] = __builtin_amdgcn_mfma_f32_16x16x32_bf16(ah[ks][i], bl, accP[i][j], 0, 0, 0);
                    accP[i][j] = __builtin_amdgcn_mfma_f32_16x16x32_bf16(al[ks][i], bh, accP[i][j], 0, 0, 0);
                    accG[i][j] = __builtin_amdgcn_mfma_f32_16x16x32_bf16(ag[ks][i], bh, accG[i][j], 0, 0, 0);
                }
            }
    }
#pragma unroll
    for (int i = 0; i < 2; i++) {
        int mrow = wm + i * 16 + quad * 4;
#pragma unroll
        for (int j = 0; j < 2; j++) {
            int n = n0 + j * 16 + col;
            unsigned short h[4], l[4];
#pragma unroll
            for (int e = 0; e < 4; e++) {
                float v = accP[i][j][e] + bp[mrow + e];
                h[e] = f2bf(v);
                l[e] = f2bf(v - bf2f(h[e]));
            }
            uint2 hv, lv;
            hv.x = (unsigned int)h[0] | ((unsigned int)h[1] << 16);
            hv.y = (unsigned int)h[2] | ((unsigned int)h[3] << 16);
            lv.x = (unsigned int)l[0] | ((unsigned int)l[1] << 16);
            lv.y = (unsigned int)l[2] | ((unsigned int)l[3] << 16);
            *(uint2*)&phiH[((size_t)(b * NN + n)) * NCI + mrow] = hv;
            *(uint2*)&phiL[((size_t)(b * NN + n)) * NCI + mrow] = lv;
#pragma unroll
            for (int r = 0; r < 4; r++)
                gout[((size_t)(b * NCI + mrow + r)) * NN + n] = f2bf(accG[i][j][r] + bg[mrow + r]);
        }
    }
}

// ---------------------------------------------------------------- K2: fused attention, 8 waves
// Block: batch b, 64 queries. Wave (qg,kh): 16 queries (qg), 32-key half (kh)
// for QK; c-half (kh) for PV. Associative exp2 softmax (no max-sub) -> per-wave
// partial li merged once at the end. LDS regions phase-overlaid (88 KB arena).
__global__ __launch_bounds__(512, 2) void k_attn(
    const float* __restrict__ x,
    const unsigned short* __restrict__ WtH, const unsigned short* __restrict__ WtL,
    const float* __restrict__ bt,
    const unsigned short* __restrict__ phiH, const unsigned short* __restrict__ phiL,
    const unsigned short* __restrict__ gmat,
    const unsigned short* __restrict__ WoH, const float* __restrict__ bo,
    float* __restrict__ y) {
    const float LOG2E = 1.4426950408889634f;
    __shared__ __align__(16) char smem[90112];
    unsigned short* sThH = (unsigned short*)(smem);            // prologue out [64 q][136]
    unsigned short* sThL = (unsigned short*)(smem + 17408);
    unsigned short* sWth = (unsigned short*)(smem + 34816);    // prologue [128 ci][72]
    unsigned short* sWtl = (unsigned short*)(smem + 53248);
    unsigned short* sXh  = (unsigned short*)(smem + 71680);    // prologue [64 n][72]
    unsigned short* sXl  = (unsigned short*)(smem + 80896);
    unsigned short* sPhiH = (unsigned short*)(smem);           // main [64 m][136]
    unsigned short* sPhiL = (unsigned short*)(smem + 17408);
    unsigned short* sG    = (unsigned short*)(smem + 34816);   // main [128 c][72]
    unsigned short* sPall = (unsigned short*)(smem + 53248);   // [4 qg][16 q][72]
    float* sLi            = (float*)(smem + 62464);            // [8 waves][16 q]
    unsigned short* sO    = (unsigned short*)(smem);           // epilogue [64 q][136]
    unsigned short* sWo   = (unsigned short*)(smem + 17408);   // epilogue [256 o][136]

    const int id = blockIdx.x;
    const int xcd = id & 7, slot = id >> 3;
    const int b = xcd >> 1;
    const int n0 = (slot * 2 + (xcd & 1)) * 64;

    const int tid = threadIdx.x, lane = tid & 63, wave = tid >> 6;  // wave 0..7
    const int col = lane & 15, quad = lane >> 4;
    const int qg = wave >> 1, kh = wave & 1;

    // ---------------- prologue: theta (log2e-scaled), f32-grade split
    f32x4 th[4];
#pragma unroll
    for (int j = 0; j < 4; j++)
#pragma unroll
        for (int e = 0; e < 4; e++) th[j][e] = 0.f;
    const int wci = wave * 16;

    for (int c0 = 0; c0 < NC; c0 += 64) {
#pragma unroll
        for (int i = 0; i < 2; i++) {
            int q = tid + i * 512;
            int row = q >> 3, seg = q & 7;
            *(uint4*)&sWth[row * 72 + seg * 8] = *(const uint4*)&WtH[(size_t)row * NC + c0 + seg * 8];
            *(uint4*)&sWtl[row * 72 + seg * 8] = *(const uint4*)&WtL[(size_t)row * NC + c0 + seg * 8];
        }
        {
            int cp = tid >> 4, n4 = (tid & 15) * 4;
            const float* xp = x + ((size_t)(b * NC + c0 + 2 * cp)) * NN + n0 + n4;
            float4 a = *(const float4*)xp;
            float4 c = *(const float4*)(xp + NN);
            float av[4] = { a.x, a.y, a.z, a.w };
            float cv[4] = { c.x, c.y, c.z, c.w };
#pragma unroll
            for (int j = 0; j < 4; j++) {
                unsigned short ha = f2bf(av[j]), hc = f2bf(cv[j]);
                unsigned short la = f2bf(av[j] - bf2f(ha)), lc = f2bf(cv[j] - bf2f(hc));
                *(unsigned int*)&sXh[(n4 + j) * 72 + 2 * cp] =
                    (unsigned int)ha | ((unsigned int)hc << 16);
                *(unsigned int*)&sXl[(n4 + j) * 72 + 2 * cp] =
                    (unsigned int)la | ((unsigned int)lc << 16);
            }
        }
        __syncthreads();
#pragma unroll
        for (int ks = 0; ks < 2; ks++) {
            short8 ah = *(const short8*)&sWth[(wci + col) * 72 + ks * 32 + quad * 8];
            short8 al = *(const short8*)&sWtl[(wci + col) * 72 + ks * 32 + quad * 8];
#pragma unroll
            for (int j = 0; j < 4; j++) {
                short8 bh = *(const short8*)&sXh[(j * 16 + col) * 72 + ks * 32 + quad * 8];
                short8 bl = *(const short8*)&sXl[(j * 16 + col) * 72 + ks * 32 + quad * 8];
                th[j] = __builtin_amdgcn_mfma_f32_16x16x32_bf16(ah, bh, th[j], 0, 0, 0);
                th[j] = __builtin_amdgcn_mfma_f32_16x16x32_bf16(ah, bl, th[j], 0, 0, 0);
                th[j] = __builtin_amdgcn_mfma_f32_16x16x32_bf16(al, bh, th[j], 0, 0, 0);
            }
        }
        __syncthreads();
    }
    {
        int ci = wci + quad * 4;
#pragma unroll
        for (int j = 0; j < 4; j++) {
            int q = j * 16 + col;
            unsigned short h[4], l[4];
#pragma unroll
            for (int e = 0; e < 4; e++) {
                float v = th[j][e] + bt[ci + e] * LOG2E;
                h[e] = f2bf(v);
                l[e] = f2bf(v - bf2f(h[e]));
            }
            uint2 hv, lv;
            hv.x = (unsigned int)h[0] | ((unsigned int)h[1] << 16);
            hv.y = (unsigned int)h[2] | ((unsigned int)h[3] << 16);
            lv.x = (unsigned int)l[0] | ((unsigned int)l[1] << 16);
            lv.y = (unsigned int)l[2] | ((unsigned int)l[3] << 16);
            *(uint2*)&sThH[q * 136 + ci] = hv;
            *(uint2*)&sThL[q * 136 + ci] = lv;
        }
    }
    __syncthreads();
    short8 qh[4], ql[4];
#pragma unroll
    for (int ks = 0; ks < 4; ks++) {
        qh[ks] = *(const short8*)&sThH[(qg * 16 + col) * 136 + ks * 32 + quad * 8];
        ql[ks] = *(const short8*)&sThL[(qg * 16 + col) * 136 + ks * 32 + quad * 8];
    }

    // ---------------- main K-loop
    f32x4 oacc[4];
#pragma unroll
    for (int i = 0; i < 4; i++)
#pragma unroll
        for (int e = 0; e < 4; e++) oacc[i][e] = 0.f;
    float li[4] = { 0.f, 0.f, 0.f, 0.f };

    for (int m0 = 0; m0 < NN; m0 += 64) {
        __syncthreads();   // prev tile LDS reads done (first iter: qh/ql reads done)
#pragma unroll
        for (int i = 0; i < 2; i++) {
            int q = tid + i * 512;
            int row = q >> 4, seg = q & 15;
            size_t src = ((size_t)(b * NN + m0 + row)) * NCI + seg * 8;
            *(uint4*)&sPhiH[row * 136 + seg * 8] = *(const uint4*)&phiH[src];
            *(uint4*)&sPhiL[row * 136 + seg * 8] = *(const uint4*)&phiL[src];
        }
#pragma unroll
        for (int i = 0; i < 2; i++) {
            int q = tid + i * 512;
            int row = q >> 3, seg = q & 7;
            *(uint4*)&sG[row * 72 + seg * 8] =
                *(const uint4*)&gmat[((size_t)(b * NCI + row)) * NN + m0 + seg * 8];
        }
        __syncthreads();

        // QK: this wave's 32-key half
        f32x4 S[2];
#pragma unroll
        for (int mtl = 0; mtl < 2; mtl++) {
            f32x4 a;
#pragma unroll
            for (int e = 0; e < 4; e++) a[e] = 0.f;
            int kcol = kh * 32 + mtl * 16 + col;
#pragma unroll
            for (int ks = 0; ks < 4; ks++) {
                short8 ph = *(const short8*)&sPhiH[kcol * 136 + ks * 32 + quad * 8];
                short8 pl = *(const short8*)&sPhiL[kcol * 136 + ks * 32 + quad * 8];
                a = __builtin_amdgcn_mfma_f32_16x16x32_bf16(qh[ks], ph, a, 0, 0, 0);
                a = __builtin_amdgcn_mfma_f32_16x16x32_bf16(qh[ks], pl, a, 0, 0, 0);
                a = __builtin_amdgcn_mfma_f32_16x16x32_bf16(ql[ks], ph, a, 0, 0, 0);
            }
            S[mtl] = a;
        }
        float pv[2][4];
#pragma unroll
        for (int r = 0; r < 4; r++) {
            float rs = 0.f;
#pragma unroll
            for (int mtl = 0; mtl < 2; mtl++) {
                float p = exp2f(S[mtl][r]);
                pv[mtl][r] = p;
                rs += p;
            }
#pragma unroll
            for (int off = 1; off < 16; off <<= 1) rs += __shfl_xor(rs, off);
            li[r] += rs;   // partial over this wave's 32 keys
        }
#pragma unroll
        for (int mtl = 0; mtl < 2; mtl++)
#pragma unroll
            for (int r = 0; r < 4; r++)
                sPall[qg * 1152 + (quad * 4 + r) * 72 + kh * 32 + mtl * 16 + col] =
                    f2bf(pv[mtl][r]);
        __syncthreads();   // P halves from both waves of the pair visible

        // PV: this wave's c-half over all 64 keys of the tile
        short8 pf[2];
#pragma unroll
        for (int ks = 0; ks < 2; ks++)
            pf[ks] = *(const short8*)&sPall[qg * 1152 + col * 72 + ks * 32 + quad * 8];
#pragma unroll
        for (int ct = 0; ct < 4; ct++)
#pragma unroll
            for (int ks = 0; ks < 2; ks++) {
                short8 af = *(const short8*)&sG[(kh * 64 + ct * 16 + col) * 72 + ks * 32 + quad * 8];
                oacc[ct] = __builtin_amdgcn_mfma_f32_16x16x32_bf16(af, pf[ks], oacc[ct], 0, 0, 0);
            }
    }

    // ---------------- merge li across key-half wave pairs
    if (col == 0) {
#pragma unroll
        for (int r = 0; r < 4; r++) sLi[wave * 16 + quad * 4 + r] = li[r];
    }
    __syncthreads();
    float inv = 1.0f / (sLi[(2 * qg) * 16 + col] + sLi[(2 * qg + 1) * 16 + col]);

    // O -> LDS (bf16), region overlays dead sPhiH
    {
        int q = qg * 16 + col;
#pragma unroll
        for (int ct = 0; ct < 4; ct++) {
            int ci = kh * 64 + ct * 16 + quad * 4;
            uint2 v;
            unsigned short p0 = f2bf(oacc[ct][0] * inv);
            unsigned short p1 = f2bf(oacc[ct][1] * inv);
            unsigned short p2 = f2bf(oacc[ct][2] * inv);
            unsigned short p3 = f2bf(oacc[ct][3] * inv);
            v.x = (unsigned int)p0 | ((unsigned int)p1 << 16);
            v.y = (unsigned int)p2 | ((unsigned int)p3 << 16);
            *(uint2*)&sO[q * 136 + ci] = v;
        }
    }
    __syncthreads();
    // stage full Wo [256 o][128 ci]
#pragma unroll
    for (int i = 0; i < 8; i++) {
        int q = tid + i * 512;
        int row = q >> 4, seg = q & 15;
        *(uint4*)&sWo[row * 136 + seg * 8] = *(const uint4*)&WoH[(size_t)row * NCI + seg * 8];
    }
    __syncthreads();
    // out-proj: wave's 32-o tile + bias + residual
    f32x4 acc[2][4];
#pragma unroll
    for (int i = 0; i < 2; i++)
#pragma unroll
        for (int j = 0; j < 4; j++)
#pragma unroll
            for (int e = 0; e < 4; e++) acc[i][j][e] = 0.f;
#pragma unroll
    for (int ks = 0; ks < 4; ks++) {
        short8 af[2];
#pragma unroll
        for (int i = 0; i < 2; i++)
            af[i] = *(const short8*)&sWo[(wave * 32 + i * 16 + col) * 136 + ks * 32 + quad * 8];
#pragma unroll
        for (int j = 0; j < 4; j++) {
            short8 bf = *(const short8*)&sO[(j * 16 + col) * 136 + ks * 32 + quad * 8];
#pragma unroll
            for (int i = 0; i < 2; i++)
                acc[i][j] = __builtin_amdgcn_mfma_f32_16x16x32_bf16(af[i], bf, acc[i][j], 0, 0, 0);
        }
    }
#pragma unroll
    for (int i = 0; i < 2; i++)
#pragma unroll
        for (int j = 0; j < 4; j++)
#pragma unroll
            for (int e = 0; e < 4; e++) {
                int o = wave * 32 + i * 16 + quad * 4 + e;
                size_t idx = ((size_t)(b * NC + o)) * NN + n0 + j * 16 + col;
                y[idx] = acc[i][j][e] + bo[o] + x[idx];
            }
}

// ---------------------------------------------------------------- launch
// ws: phiH(4M) + phiL(4M) + g(4M) + split weights(384K) ~ 12.4 MB of >=16 MB.
extern "C" void kernel_launch(void* const* d_in, const int* in_sizes, int n_in,
                              void* d_out, int out_size, void* d_ws, size_t ws_size,
                              hipStream_t stream) {
    float* y = (float*)d_out;

    bool sizes_ok = (n_in == 9) &&
        in_sizes[0] == NB * NC * NN && in_sizes[1] == NCI * NC && in_sizes[2] == NCI &&
        in_sizes[3] == NCI * NC && in_sizes[4] == NCI && in_sizes[5] == NCI * NC &&
        in_sizes[6] == NCI && in_sizes[7] == NC * NCI && in_sizes[8] == NC &&
        out_size == NB * NC * NN;
    if (!sizes_ok) {
        k_fill<<<(out_size + 255) / 256, 256, 0, stream>>>(y, 777.0f, out_size);
        return;
    }
    if (ws_size < (size_t)16 * 1024 * 1024) {
        k_fill<<<(out_size + 255) / 256, 256, 0, stream>>>(y, 555.0f, out_size);
        return;
    }

    const float* x  = (const float*)d_in[0];
    const float* tw = (const float*)d_in[1];
    const float* tb = (const float*)d_in[2];
    const float* pw = (const float*)d_in[3];
    const float* pb = (const float*)d_in[4];
    const float* gw = (const float*)d_in[5];
    const float* gb = (const float*)d_in[6];
    const float* ow = (const float*)d_in[7];
    const float* obias = (const float*)d_in[8];

    unsigned short* ws16 = (unsigned short*)d_ws;
    unsigned short* phiH = ws16;                 // [B][N][Ci] bf16 hi
    unsigned short* phiL = ws16 + 2097152;       // [B][N][Ci] bf16 lo
    unsigned short* g    = ws16 + 4194304;       // [B][Ci][N] bf16
    unsigned short* wbuf = ws16 + 6291456;       // WtH,WtL,WpH,WpL,WgH,WoH
    unsigned short* WtH = wbuf,           *WtL = wbuf + 32768;
    unsigned short* WpH = wbuf + 65536,   *WpL = wbuf + 98304;
    unsigned short* WgH = wbuf + 131072,  *WoH = wbuf + 163840;

    k_split<<<dim3(128, 4), 256, 0, stream>>>(tw, pw, gw, ow, wbuf);
    k_qkv2<<<dim3(128, NB), 256, 0, stream>>>(x, WpH, WpL, WgH, pb, gb, phiH, phiL, g);
    k_attn<<<dim3(256), 512, 0, stream>>>(x, WtH, WtL, tb, phiH, phiL, g, WoH, obias, y);
}